// Round 2
// baseline (647.162 us; speedup 1.0000x reference)
//
#include <hip/hip_runtime.h>

#define TEN 10

// ---------------------------------------------------------------------------
// Phase A: each 10-lane group computes the ordered product of L per-step
// transition matrices W_t = sum_k x[t,k] * P[k] for its chunk.
// Lane r of a group owns row r of the chunk accumulator M and the P-slice
// P[:, r, :] in registers (100 VGPRs). W is shared within the group via LDS.
//
// __launch_bounds__(256, 2): cap VGPRs at ~256 so the 100-float P slice stays
// resident (R1's kernel spilled to scratch at the default occupancy target —
// VGPR_Count=96 < 100 live values, 4300 cyc/step).  No asm memory clobbers:
// they blocked remat/hoist of the P loads and forced per-step scratch reloads.
// Same-wave LDS write->read ordering: DS ops from one wave are processed in
// order by the LDS pipe; wave_barrier() pins compiler scheduling (zero cost).
// ---------------------------------------------------------------------------
__global__ __launch_bounds__(256, 2) void automaton_chunks(
    const float* __restrict__ x, const float* __restrict__ P,
    float* __restrict__ outM, int C, int L)
{
    // 4 waves/block * 6 groups/wave * 10 rows * 12 floats (padded) = 11.25 KB
    __shared__ __align__(16) float wlds[4][6][TEN][12];

    const int tid  = threadIdx.x;
    const int wave = tid >> 6;
    const int lane = tid & 63;
    const int g    = lane / TEN;   // group within wave (0..5; 6 = idle lanes)
    const int r    = lane % TEN;   // row owned by this lane
    const int chunk = blockIdx.x * 24 + wave * 6 + g;
    if (g >= 6 || chunk >= C) return;

    // Loop-invariant P slice: p[k][j] = P[k][r][j]  (100 VGPRs)
    float p[TEN][TEN];
#pragma unroll
    for (int k = 0; k < TEN; ++k)
#pragma unroll
        for (int j = 0; j < TEN; ++j)
            p[k][j] = P[k * 100 + r * TEN + j];

    // M starts as identity; lane holds row r.
    float m[TEN];
#pragma unroll
    for (int j = 0; j < TEN; ++j) m[j] = (j == r) ? 1.0f : 0.0f;

    // x rows are 10 floats = 40 B -> 8 B aligned, so float2 loads.
    const float2* xp = reinterpret_cast<const float2*>(x) + (size_t)chunk * L * 5;
    float* wrow      = &wlds[wave][g][r][0];
    const float* wg  = &wlds[wave][g][0][0];

    // Prefetch first x row.
    float2 nx0 = xp[0], nx1 = xp[1], nx2 = xp[2], nx3 = xp[3], nx4 = xp[4];
    xp += 5;

    for (int s = 0; s < L; ++s) {
        const float xv[TEN] = {nx0.x, nx0.y, nx1.x, nx1.y, nx2.x,
                               nx2.y, nx3.x, nx3.y, nx4.x, nx4.y};
        // Prefetch next x row (independent of this step's chain).
        if (s + 1 < L) {
            nx0 = xp[0]; nx1 = xp[1]; nx2 = xp[2]; nx3 = xp[3]; nx4 = xp[4];
            xp += 5;
        }
        // Build W row r: w[j] = sum_k x[k] * P[k][r][j]   (100 FMA)
        float w[TEN];
#pragma unroll
        for (int j = 0; j < TEN; ++j) {
            float acc = xv[0] * p[0][j];
#pragma unroll
            for (int k = 1; k < TEN; ++k) acc = fmaf(xv[k], p[k][j], acc);
            w[j] = acc;
        }
        // Publish row to LDS (rows padded to 12 floats; 48B stride keeps 16B align).
        reinterpret_cast<float4*>(wrow)[0]     = make_float4(w[0], w[1], w[2], w[3]);
        reinterpret_cast<float4*>(wrow)[1]     = make_float4(w[4], w[5], w[6], w[7]);
        reinterpret_cast<float2*>(wrow + 8)[0] = make_float2(w[8], w[9]);
        __builtin_amdgcn_wave_barrier();   // pin write -> read order (free)

        // M row update: mn[j] = sum_a m[a] * W[a][j]   (100 FMA)
        float mn[TEN] = {0, 0, 0, 0, 0, 0, 0, 0, 0, 0};
#pragma unroll
        for (int a = 0; a < TEN; ++a) {
            const float4 wa0 = reinterpret_cast<const float4*>(wg + a * 12)[0];
            const float4 wa1 = reinterpret_cast<const float4*>(wg + a * 12)[1];
            const float2 wa2 = reinterpret_cast<const float2*>(wg + a * 12 + 8)[0];
            const float ma = m[a];
            mn[0] = fmaf(ma, wa0.x, mn[0]);
            mn[1] = fmaf(ma, wa0.y, mn[1]);
            mn[2] = fmaf(ma, wa0.z, mn[2]);
            mn[3] = fmaf(ma, wa0.w, mn[3]);
            mn[4] = fmaf(ma, wa1.x, mn[4]);
            mn[5] = fmaf(ma, wa1.y, mn[5]);
            mn[6] = fmaf(ma, wa1.z, mn[6]);
            mn[7] = fmaf(ma, wa1.w, mn[7]);
            mn[8] = fmaf(ma, wa2.x, mn[8]);
            mn[9] = fmaf(ma, wa2.y, mn[9]);
        }
#pragma unroll
        for (int j = 0; j < TEN; ++j) m[j] = mn[j];
        __builtin_amdgcn_wave_barrier();   // pin read -> next write order (free)
    }

    float* dst = outM + (size_t)chunk * 100 + r * TEN;
#pragma unroll
    for (int j = 0; j < TEN; ++j) dst[j] = m[j];
}

// ---------------------------------------------------------------------------
// Reduction: group g multiplies R consecutive matrices (in order) into one.
// Double-buffered register prefetch hides the load latency of matrix mm+1
// behind the 200-FMA update with matrix mm.
// ---------------------------------------------------------------------------
__device__ __forceinline__ float bel(const float4* b, int i)
{
    const float4 v = b[i >> 2];
    switch (i & 3) {
        case 0: return v.x;
        case 1: return v.y;
        case 2: return v.z;
        default: return v.w;
    }
}

__global__ __launch_bounds__(256, 2) void reduce_chain(
    const float* __restrict__ in, float* __restrict__ out, int nOut, int R)
{
    const int tid  = threadIdx.x;
    const int wave = tid >> 6;
    const int lane = tid & 63;
    const int g    = lane / TEN;
    const int r    = lane % TEN;
    const int gpb  = (blockDim.x >> 6) * 6;
    const int grp  = blockIdx.x * gpb + wave * 6 + g;
    if (g >= 6 || grp >= nOut) return;

    const float* base = in + (size_t)grp * R * 100;
    float a[TEN];
#pragma unroll
    for (int j = 0; j < TEN; ++j) a[j] = base[r * TEN + j];

    // Prefetch matrix 1.
    float4 cur[25];
    {
        const float4* b4 = reinterpret_cast<const float4*>(base + 100);
#pragma unroll
        for (int q = 0; q < 25; ++q) cur[q] = b4[q];
    }

    for (int mm = 1; mm < R; ++mm) {
        float4 nxt[25];
        if (mm + 1 < R) {
            const float4* b4 = reinterpret_cast<const float4*>(base + (size_t)(mm + 1) * 100);
#pragma unroll
            for (int q = 0; q < 25; ++q) nxt[q] = b4[q];
        }
        float an[TEN] = {0, 0, 0, 0, 0, 0, 0, 0, 0, 0};
#pragma unroll
        for (int aa = 0; aa < TEN; ++aa) {
            const float ma = a[aa];
#pragma unroll
            for (int j = 0; j < TEN; ++j)
                an[j] = fmaf(ma, bel(cur, aa * TEN + j), an[j]);
        }
#pragma unroll
        for (int j = 0; j < TEN; ++j) a[j] = an[j];
        if (mm + 1 < R) {
#pragma unroll
            for (int q = 0; q < 25; ++q) cur[q] = nxt[q];
        }
    }
    float* dst = out + (size_t)grp * 100 + r * TEN;
#pragma unroll
    for (int j = 0; j < TEN; ++j) dst[j] = a[j];
}

// ---------------------------------------------------------------------------
// Finalize: multiply the last n matrices (n small), apply start and accept.
// ---------------------------------------------------------------------------
__global__ void finalize(const float* __restrict__ in, int n,
                         const float* __restrict__ start, const float* __restrict__ acc,
                         float* __restrict__ outv)
{
    __shared__ float sred[TEN][12];
    const int lane = threadIdx.x;

    if (lane < TEN) {
        const int r = lane;
        float a[TEN];
#pragma unroll
        for (int j = 0; j < TEN; ++j) a[j] = in[r * TEN + j];
        for (int mm = 1; mm < n; ++mm) {
            const float4* b4 = reinterpret_cast<const float4*>(in + (size_t)mm * 100);
            float4 b[25];
#pragma unroll
            for (int q = 0; q < 25; ++q) b[q] = b4[q];
            float an[TEN] = {0, 0, 0, 0, 0, 0, 0, 0, 0, 0};
#pragma unroll
            for (int aa = 0; aa < TEN; ++aa) {
                const float ma = a[aa];
#pragma unroll
                for (int j = 0; j < TEN; ++j)
                    an[j] = fmaf(ma, bel(b, aa * TEN + j), an[j]);
            }
#pragma unroll
            for (int j = 0; j < TEN; ++j) a[j] = an[j];
        }
        const float sr = start[r];
#pragma unroll
        for (int j = 0; j < TEN; ++j) sred[r][j] = sr * a[j];
    }
    __syncthreads();
    if (lane == 0) {
        float o0 = 0.0f, o1 = 0.0f;
#pragma unroll
        for (int j = 0; j < TEN; ++j) {
            float t = 0.0f;
#pragma unroll
            for (int rr = 0; rr < TEN; ++rr) t += sred[rr][j];
            o0 = fmaf(t, acc[j * 2 + 0], o0);
            o1 = fmaf(t, acc[j * 2 + 1], o1);
        }
        outv[0] = o0;
        outv[1] = o1;
    }
}

extern "C" void kernel_launch(void* const* d_in, const int* in_sizes, int n_in,
                              void* d_out, int out_size, void* d_ws, size_t ws_size,
                              hipStream_t stream)
{
    const float* x     = (const float*)d_in[0];
    const float* P     = (const float*)d_in[1];
    const float* start = (const float*)d_in[2];
    const float* acc   = (const float*)d_in[3];
    float* out         = (float*)d_out;

    const long long T = (long long)in_sizes[0] / TEN;  // 2,097,152 steps

    // Workspace: C chunk matrices + 512 level-1 + 16 level-2, 100 floats each.
    long long C = 2048;
    if (ws_size >= (size_t)(16384 + 512 + 16) * 400)      C = 16384;
    else if (ws_size >= (size_t)(8192 + 512 + 16) * 400)  C = 8192;
    else if (ws_size >= (size_t)(4096 + 512 + 16) * 400)  C = 4096;
    const int L  = (int)(T / C);       // steps per chunk (T is a power of two)
    const int R1 = (int)(C / 512);     // level-1 radix

    float* ws1 = (float*)d_ws;                    // [C][10][10]
    float* ws2 = ws1 + (size_t)C * 100;           // [512][10][10]
    float* ws3 = ws2 + (size_t)512 * 100;         // [16][10][10]

    automaton_chunks<<<(int)((C + 23) / 24), 256, 0, stream>>>(x, P, ws1, (int)C, L);
    reduce_chain<<<(512 + 23) / 24, 256, 0, stream>>>(ws1, ws2, 512, R1);   // C -> 512
    reduce_chain<<<1, 192, 0, stream>>>(ws2, ws3, 16, 32);                  // 512 -> 16
    finalize<<<1, 64, 0, stream>>>(ws3, 16, start, acc, out);
}

// Round 3
// 300.804 us; speedup vs baseline: 2.1514x; 2.1514x over previous
//
#include <hip/hip_runtime.h>

#define TEN 10

// ---------------------------------------------------------------------------
// Phase A: each 10-lane group computes the ordered product of L per-step
// transition matrices W_t = sum_k x[t,k] * P[k] for its chunk.
// Lane r of a group owns row r of the chunk accumulator M and the P-slice
// P[:, r, :] in registers (100 VGPRs). W is shared within the group via LDS.
//
// amdgpu_waves_per_eu(2,2): __launch_bounds__(256,2) alone did NOT stop the
// scheduler from targeting max occupancy — it squeezed pressure to 96 VGPRs
// and spilled the loop-invariant P slice to scratch (R1/R2: 96 VGPRs, 1590
// cyc/step, VALUBusy 30%). Setting the MAX waves/EU to 2 caps the scheduler's
// occupancy target so ~160 live VGPRs stay resident.
// ---------------------------------------------------------------------------
__global__ __launch_bounds__(256)
__attribute__((amdgpu_waves_per_eu(2, 2)))
void automaton_chunks(
    const float* __restrict__ x, const float* __restrict__ P,
    float* __restrict__ outM, int C, int L)
{
    // 4 waves/block * 6 groups/wave * 10 rows * 12 floats (padded) = 11.25 KB
    // Row stride 12 floats (48 B) staggers the 6 groups across banks.
    __shared__ __align__(16) float wlds[4][6][TEN][12];

    const int tid  = threadIdx.x;
    const int wave = tid >> 6;
    const int lane = tid & 63;
    const int g    = lane / TEN;   // group within wave (0..5; 6 = idle lanes)
    const int r    = lane % TEN;   // row owned by this lane
    const int chunk = blockIdx.x * 24 + wave * 6 + g;
    if (g >= 6 || chunk >= C) return;

    // Loop-invariant P slice: p[k][j] = P[k][r][j]  (100 VGPRs)
    float p[TEN][TEN];
#pragma unroll
    for (int k = 0; k < TEN; ++k)
#pragma unroll
        for (int j = 0; j < TEN; ++j)
            p[k][j] = P[k * 100 + r * TEN + j];

    // M starts as identity; lane holds row r.
    float m[TEN];
#pragma unroll
    for (int j = 0; j < TEN; ++j) m[j] = (j == r) ? 1.0f : 0.0f;

    // x rows are 10 floats = 40 B -> 8 B aligned, so float2 loads.
    const float2* xp = reinterpret_cast<const float2*>(x) + (size_t)chunk * L * 5;
    float* wrow      = &wlds[wave][g][r][0];
    const float* wg  = &wlds[wave][g][0][0];

    // Prefetch first x row.
    float2 nx0 = xp[0], nx1 = xp[1], nx2 = xp[2], nx3 = xp[3], nx4 = xp[4];
    xp += 5;

    for (int s = 0; s < L; ++s) {
        const float xv[TEN] = {nx0.x, nx0.y, nx1.x, nx1.y, nx2.x,
                               nx2.y, nx3.x, nx3.y, nx4.x, nx4.y};
        // Prefetch next x row (independent of this step's chain).
        if (s + 1 < L) {
            nx0 = xp[0]; nx1 = xp[1]; nx2 = xp[2]; nx3 = xp[3]; nx4 = xp[4];
            xp += 5;
        }
        // Build W row r: w[j] = sum_k x[k] * P[k][r][j]   (100 FMA)
        float w[TEN];
#pragma unroll
        for (int j = 0; j < TEN; ++j) {
            float acc = xv[0] * p[0][j];
#pragma unroll
            for (int k = 1; k < TEN; ++k) acc = fmaf(xv[k], p[k][j], acc);
            w[j] = acc;
        }
        // Publish row to LDS (rows padded to 12 floats; 48B stride keeps 16B align).
        reinterpret_cast<float4*>(wrow)[0]     = make_float4(w[0], w[1], w[2], w[3]);
        reinterpret_cast<float4*>(wrow)[1]     = make_float4(w[4], w[5], w[6], w[7]);
        reinterpret_cast<float2*>(wrow + 8)[0] = make_float2(w[8], w[9]);
        __builtin_amdgcn_wave_barrier();   // pin write -> read order (free)

        // M row update: mn[j] = sum_a m[a] * W[a][j]   (100 FMA)
        // All 10 lanes of a group read the same address -> LDS broadcast.
        float mn[TEN] = {0, 0, 0, 0, 0, 0, 0, 0, 0, 0};
#pragma unroll
        for (int a = 0; a < TEN; ++a) {
            const float4 wa0 = reinterpret_cast<const float4*>(wg + a * 12)[0];
            const float4 wa1 = reinterpret_cast<const float4*>(wg + a * 12)[1];
            const float2 wa2 = reinterpret_cast<const float2*>(wg + a * 12 + 8)[0];
            const float ma = m[a];
            mn[0] = fmaf(ma, wa0.x, mn[0]);
            mn[1] = fmaf(ma, wa0.y, mn[1]);
            mn[2] = fmaf(ma, wa0.z, mn[2]);
            mn[3] = fmaf(ma, wa0.w, mn[3]);
            mn[4] = fmaf(ma, wa1.x, mn[4]);
            mn[5] = fmaf(ma, wa1.y, mn[5]);
            mn[6] = fmaf(ma, wa1.z, mn[6]);
            mn[7] = fmaf(ma, wa1.w, mn[7]);
            mn[8] = fmaf(ma, wa2.x, mn[8]);
            mn[9] = fmaf(ma, wa2.y, mn[9]);
        }
#pragma unroll
        for (int j = 0; j < TEN; ++j) m[j] = mn[j];
        __builtin_amdgcn_wave_barrier();   // pin read -> next write order (free)
    }

    float* dst = outM + (size_t)chunk * 100 + r * TEN;
#pragma unroll
    for (int j = 0; j < TEN; ++j) dst[j] = m[j];
}

// ---------------------------------------------------------------------------
// Reduction: group g multiplies R consecutive matrices (in order) into one.
// LOW register pressure by design: matrix B is never held in an array —
// each row is streamed as 5 float2 loads consumed immediately (~40 live
// VGPRs). R2's float4 cur[25]/nxt[25] arrays spilled to scratch and made
// every serial iteration a ~500-cycle scratch round-trip.
// ---------------------------------------------------------------------------
__global__ __launch_bounds__(256) void reduce_chain(
    const float* __restrict__ in, float* __restrict__ out, int nOut, int R)
{
    const int tid  = threadIdx.x;
    const int wave = tid >> 6;
    const int lane = tid & 63;
    const int g    = lane / TEN;
    const int r    = lane % TEN;
    const int gpb  = (blockDim.x >> 6) * 6;
    const int grp  = blockIdx.x * gpb + wave * 6 + g;
    if (g >= 6 || grp >= nOut) return;

    const float* base = in + (size_t)grp * R * 100;

    // a = row r of matrix 0 (row offset 40 B -> 8 B aligned -> float2 loads)
    float a[TEN];
    {
        const float2* r0 = reinterpret_cast<const float2*>(base + r * TEN);
        const float2 a0 = r0[0], a1 = r0[1], a2 = r0[2], a3 = r0[3], a4 = r0[4];
        a[0] = a0.x; a[1] = a0.y; a[2] = a1.x; a[3] = a1.y; a[4] = a2.x;
        a[5] = a2.y; a[6] = a3.x; a[7] = a3.y; a[8] = a4.x; a[9] = a4.y;
    }

    for (int mm = 1; mm < R; ++mm) {
        const float* B = base + (size_t)mm * 100;
        float an[TEN] = {0, 0, 0, 0, 0, 0, 0, 0, 0, 0};
#pragma unroll
        for (int aa = 0; aa < TEN; ++aa) {
            const float2* br = reinterpret_cast<const float2*>(B + aa * TEN);
            const float2 b0 = br[0], b1 = br[1], b2 = br[2], b3 = br[3], b4 = br[4];
            const float ma = a[aa];
            an[0] = fmaf(ma, b0.x, an[0]);
            an[1] = fmaf(ma, b0.y, an[1]);
            an[2] = fmaf(ma, b1.x, an[2]);
            an[3] = fmaf(ma, b1.y, an[3]);
            an[4] = fmaf(ma, b2.x, an[4]);
            an[5] = fmaf(ma, b2.y, an[5]);
            an[6] = fmaf(ma, b3.x, an[6]);
            an[7] = fmaf(ma, b3.y, an[7]);
            an[8] = fmaf(ma, b4.x, an[8]);
            an[9] = fmaf(ma, b4.y, an[9]);
        }
#pragma unroll
        for (int j = 0; j < TEN; ++j) a[j] = an[j];
    }
    float* dst = out + (size_t)grp * 100 + r * TEN;
#pragma unroll
    for (int j = 0; j < TEN; ++j) dst[j] = a[j];
}

// ---------------------------------------------------------------------------
// Finalize: multiply the last n matrices (n tiny), apply start and accept.
// Same streamed-row style as reduce_chain (no spillable arrays).
// ---------------------------------------------------------------------------
__global__ void finalize(const float* __restrict__ in, int n,
                         const float* __restrict__ start, const float* __restrict__ acc,
                         float* __restrict__ outv)
{
    __shared__ float sred[TEN][12];
    const int lane = threadIdx.x;

    if (lane < TEN) {
        const int r = lane;
        float a[TEN];
        {
            const float2* r0 = reinterpret_cast<const float2*>(in + r * TEN);
            const float2 a0 = r0[0], a1 = r0[1], a2 = r0[2], a3 = r0[3], a4 = r0[4];
            a[0] = a0.x; a[1] = a0.y; a[2] = a1.x; a[3] = a1.y; a[4] = a2.x;
            a[5] = a2.y; a[6] = a3.x; a[7] = a3.y; a[8] = a4.x; a[9] = a4.y;
        }
        for (int mm = 1; mm < n; ++mm) {
            const float* B = in + (size_t)mm * 100;
            float an[TEN] = {0, 0, 0, 0, 0, 0, 0, 0, 0, 0};
#pragma unroll
            for (int aa = 0; aa < TEN; ++aa) {
                const float2* br = reinterpret_cast<const float2*>(B + aa * TEN);
                const float2 b0 = br[0], b1 = br[1], b2 = br[2], b3 = br[3], b4 = br[4];
                const float ma = a[aa];
                an[0] = fmaf(ma, b0.x, an[0]);
                an[1] = fmaf(ma, b0.y, an[1]);
                an[2] = fmaf(ma, b1.x, an[2]);
                an[3] = fmaf(ma, b1.y, an[3]);
                an[4] = fmaf(ma, b2.x, an[4]);
                an[5] = fmaf(ma, b2.y, an[5]);
                an[6] = fmaf(ma, b3.x, an[6]);
                an[7] = fmaf(ma, b3.y, an[7]);
                an[8] = fmaf(ma, b4.x, an[8]);
                an[9] = fmaf(ma, b4.y, an[9]);
            }
#pragma unroll
            for (int j = 0; j < TEN; ++j) a[j] = an[j];
        }
        const float sr = start[r];
#pragma unroll
        for (int j = 0; j < TEN; ++j) sred[r][j] = sr * a[j];
    }
    __syncthreads();
    if (lane == 0) {
        float o0 = 0.0f, o1 = 0.0f;
#pragma unroll
        for (int j = 0; j < TEN; ++j) {
            float t = 0.0f;
#pragma unroll
            for (int rr = 0; rr < TEN; ++rr) t += sred[rr][j];
            o0 = fmaf(t, acc[j * 2 + 0], o0);
            o1 = fmaf(t, acc[j * 2 + 1], o1);
        }
        outv[0] = o0;
        outv[1] = o1;
    }
}

extern "C" void kernel_launch(void* const* d_in, const int* in_sizes, int n_in,
                              void* d_out, int out_size, void* d_ws, size_t ws_size,
                              hipStream_t stream)
{
    const float* x     = (const float*)d_in[0];
    const float* P     = (const float*)d_in[1];
    const float* start = (const float*)d_in[2];
    const float* acc   = (const float*)d_in[3];
    float* out         = (float*)d_out;

    const long long T = (long long)in_sizes[0] / TEN;  // 2,097,152 steps

    // Workspace: C + 1024 + 64 + 4 matrices, 100 floats each.
    const size_t tail = (size_t)(1024 + 64 + 4) * 400;
    long long C = 2048;
    if (ws_size >= (size_t)16384 * 400 + tail)      C = 16384;
    else if (ws_size >= (size_t)8192 * 400 + tail)  C = 8192;
    else if (ws_size >= (size_t)4096 * 400 + tail)  C = 4096;
    const int L  = (int)(T / C);         // steps per chunk (T is a power of two)
    const int R1 = (int)(C / 1024);      // level-1 radix (16 for C=16384)

    float* ws1 = (float*)d_ws;                    // [C][10][10]
    float* ws2 = ws1 + (size_t)C * 100;           // [1024][10][10]
    float* ws3 = ws2 + (size_t)1024 * 100;        // [64][10][10]
    float* ws4 = ws3 + (size_t)64 * 100;          // [4][10][10]

    automaton_chunks<<<(int)((C + 23) / 24), 256, 0, stream>>>(x, P, ws1, (int)C, L);
    reduce_chain<<<(1024 + 23) / 24, 256, 0, stream>>>(ws1, ws2, 1024, R1);  // C -> 1024
    reduce_chain<<<(64 + 23) / 24, 256, 0, stream>>>(ws2, ws3, 64, 16);      // 1024 -> 64
    reduce_chain<<<1, 64, 0, stream>>>(ws3, ws4, 4, 16);                     // 64 -> 4
    finalize<<<1, 64, 0, stream>>>(ws4, 4, start, acc, out);
}